// Round 1
// baseline (194.537 us; speedup 1.0000x reference)
//
#include <hip/hip_runtime.h>
#include <hip/hip_bf16.h>
#include <stdint.h>

#define PDIM 4096
#define KSEL 3687.0f
#define NITER 50

typedef unsigned short ushort_t;
typedef __attribute__((ext_vector_type(8))) __bf16 bf16x8;
typedef __attribute__((ext_vector_type(4))) float f32x4;

typedef __attribute__((address_space(3))) void lds_void;
typedef __attribute__((address_space(1))) const void glob_void;

__device__ __forceinline__ ushort_t f32_to_bf16_rne(float f) {
  union { float f; uint32_t u; } v; v.f = f;
  uint32_t r = 0x7FFFu + ((v.u >> 16) & 1u);
  return (ushort_t)((v.u + r) >> 16);
}

__device__ __forceinline__ void async_cp16(const void* g, void* l) {
  __builtin_amdgcn_global_load_lds((glob_void*)g, (lds_void*)l, 16, 0, 0);
}

// ---------------- Kernel 1: Dykstra soft-top-k mask ----------------
__global__ __launch_bounds__(256) void dykstra_kernel(
    const float* __restrict__ alpha, float* __restrict__ a_out) {
  __shared__ float red[8];
  const int tid = threadIdx.x;
  const int lane = tid & 63;
  const int wv = tid >> 6;
  float x[16], p[16], q[16];
#pragma unroll
  for (int i = 0; i < 16; ++i) {
    x[i] = alpha[i * 256 + tid] * 100.0f;  // s = alpha / 0.01
    p[i] = 0.0f;
    q[i] = 0.0f;
  }
  for (int it = 0; it < NITER; ++it) {
    float t[16];
    float loc = 0.0f;
#pragma unroll
    for (int i = 0; i < 16; ++i) { t[i] = x[i] + p[i]; loc += t[i]; }
#pragma unroll
    for (int off = 32; off > 0; off >>= 1) loc += __shfl_down(loc, off, 64);
    const int slot = (it & 1) * 4;
    if (lane == 0) red[slot + wv] = loc;
    __syncthreads();
    const float tot = red[slot] + red[slot + 1] + red[slot + 2] + red[slot + 3];
    const float corr = (KSEL - tot) * (1.0f / 4096.0f);
#pragma unroll
    for (int i = 0; i < 16; ++i) {
      const float y = t[i] + corr;
      p[i] = t[i] - y;
      const float u = y + q[i];
      const float xn = fminf(fmaxf(u, 0.0f), 1.0f);
      q[i] = u - xn;
      x[i] = xn;
    }
  }
#pragma unroll
  for (int i = 0; i < 16; ++i) a_out[i * 256 + tid] = x[i];
}

// ---------------- Kernel 2: x fp32 -> bf16 ----------------
__global__ __launch_bounds__(256) void xconv_kernel(
    const float* __restrict__ x, ushort_t* __restrict__ Xb, int n4) {
  const int i = blockIdx.x * 256 + threadIdx.x;
  if (i >= n4) return;
  const float4 v = ((const float4*)x)[i];
  ushort4 o;
  o.x = f32_to_bf16_rne(v.x);
  o.y = f32_to_bf16_rne(v.y);
  o.z = f32_to_bf16_rne(v.z);
  o.w = f32_to_bf16_rne(v.w);
  ((ushort4*)Xb)[i] = o;
}

// ---------------- Kernel 3: materialize W (row-major bf16) ----------------
// W[r][c] = a[(r-c) mod 4096] * V[(r-c) mod 4096][c]
// 64x64 W tile per block; loads a 128-row band of V via LDS (stride 66 pad:
// diagonal read addr = C - 65*tx -> bank stride 1 -> conflict-free).
__global__ __launch_bounds__(256) void wmat_kernel(
    const float* __restrict__ V, const float* __restrict__ a,
    ushort_t* __restrict__ Wb) {
  __shared__ float vt[128][66];
  const int tx = threadIdx.x;  // 0..63
  const int tw = threadIdx.y;  // 0..3
  const int c0 = blockIdx.x * 64;
  const int r0 = blockIdx.y * 64;
  const int dbase = (r0 - c0 - 63 + 2 * PDIM) & (PDIM - 1);
#pragma unroll
  for (int ld = tw; ld < 128; ld += 4) {
    const int d = (dbase + ld) & (PDIM - 1);
    vt[ld][tx] = a[d] * V[(size_t)d * PDIM + c0 + tx];
  }
  __syncthreads();
#pragma unroll
  for (int ry = tw; ry < 64; ry += 4) {
    const int ld = ry - tx + 63;  // 0..126
    Wb[(size_t)(r0 + ry) * PDIM + c0 + tx] = f32_to_bf16_rne(vt[ld][tx]);
  }
}

// ---------------- Kernel 4: bf16 MFMA GEMM ----------------
// C[M][4096] = Xb[M][4096] * Wb^T ; Wb is [N][K] row-major (= B^T input).
// BM=64 BN=128 BK=64; 4 waves, each computes 64x32 (4 m-tiles x 2 n-tiles).
// LDS chunk layout XOR-swizzled: chunk(row, j) at row*8 + (j ^ (row&7)),
// realized through the global gather pattern (global_load_lds LDS side is
// fixed to base + lane*16).
__global__ __launch_bounds__(256) void gemm_kernel(
    const ushort_t* __restrict__ Xb, const ushort_t* __restrict__ Wb,
    float* __restrict__ out, int M) {
  constexpr int Kdim = 4096, Ndim = 4096;
  __shared__ __align__(16) ushort_t As[64 * 64];
  __shared__ __align__(16) ushort_t Bs[128 * 64];
  const int tid = threadIdx.x;
  const int lane = tid & 63;
  const int w = tid >> 6;
  const int l15 = lane & 15;
  const int quad = lane >> 4;
  const int m0 = blockIdx.y * 64;
  const int n0 = blockIdx.x * 128;
  const int arow = lane >> 3;  // 0..7 within an issue
  const int aslot = lane & 7;

  f32x4 acc[4][2];
#pragma unroll
  for (int mt = 0; mt < 4; ++mt)
#pragma unroll
    for (int nt = 0; nt < 2; ++nt) acc[mt][nt] = (f32x4){0.f, 0.f, 0.f, 0.f};

  for (int it = 0; it < Kdim / 64; ++it) {
    const int k0 = it * 64;
    // stage A tile: 8 issues of 64 lanes x 16B (8 rows each)
#pragma unroll
    for (int s = w; s < 8; s += 4) {
      const int row = s * 8 + arow;
      const int j = aslot ^ (row & 7);
      const ushort_t* g = Xb + (size_t)(m0 + row) * Kdim + k0 + j * 8;
      async_cp16(g, (char*)As + (size_t)s * 1024);
    }
    // stage B tile: 16 issues
#pragma unroll
    for (int s = w; s < 16; s += 4) {
      const int row = s * 8 + arow;
      const int j = aslot ^ (row & 7);
      const ushort_t* g = Wb + (size_t)(n0 + row) * Kdim + k0 + j * 8;
      async_cp16(g, (char*)Bs + (size_t)s * 1024);
    }
    __syncthreads();
#pragma unroll
    for (int kk = 0; kk < 64; kk += 32) {
      bf16x8 af[4], bfv[2];
      const int cj = (kk >> 3) + quad;
#pragma unroll
      for (int mt = 0; mt < 4; ++mt) {
        const int row = mt * 16 + l15;
        af[mt] = *(const bf16x8*)&As[(row * 8 + (cj ^ (row & 7))) * 8];
      }
#pragma unroll
      for (int nt = 0; nt < 2; ++nt) {
        const int row = w * 32 + nt * 16 + l15;
        bfv[nt] = *(const bf16x8*)&Bs[(row * 8 + (cj ^ (row & 7))) * 8];
      }
#pragma unroll
      for (int mt = 0; mt < 4; ++mt)
#pragma unroll
        for (int nt = 0; nt < 2; ++nt)
          acc[mt][nt] = __builtin_amdgcn_mfma_f32_16x16x32_bf16(
              af[mt], bfv[nt], acc[mt][nt], 0, 0, 0);
    }
    __syncthreads();
  }
  // epilogue: C/D layout col=lane&15 (n), row=quad*4+reg (m)
#pragma unroll
  for (int mt = 0; mt < 4; ++mt) {
#pragma unroll
    for (int nt = 0; nt < 2; ++nt) {
      const int mb = m0 + mt * 16 + quad * 4;
      const int n = n0 + w * 32 + nt * 16 + l15;
#pragma unroll
      for (int r = 0; r < 4; ++r)
        out[(size_t)(mb + r) * Ndim + n] = acc[mt][nt][r];
    }
  }
}

extern "C" void kernel_launch(void* const* d_in, const int* in_sizes, int n_in,
                              void* d_out, int out_size, void* d_ws,
                              size_t ws_size, hipStream_t stream) {
  const float* x = (const float*)d_in[0];
  const float* V = (const float*)d_in[1];
  const float* alpha = (const float*)d_in[2];
  float* out = (float*)d_out;
  const int M = in_sizes[0] / PDIM;  // 512

  // workspace layout: a (16KB) | Xb bf16 (M*4096*2) | Wb bf16 (4096*4096*2)
  float* a_mask = (float*)d_ws;
  ushort_t* Xb = (ushort_t*)((char*)d_ws + 16 * 1024);
  ushort_t* Wb = Xb + (size_t)M * PDIM;

  dykstra_kernel<<<1, 256, 0, stream>>>(alpha, a_mask);
  const int n4 = (M * PDIM) / 4;
  xconv_kernel<<<(n4 + 255) / 256, 256, 0, stream>>>(x, Xb, n4);
  wmat_kernel<<<dim3(PDIM / 64, PDIM / 64), dim3(64, 4), 0, stream>>>(V, a_mask, Wb);
  gemm_kernel<<<dim3(PDIM / 128, M / 64), 256, 0, stream>>>(Xb, Wb, out, M);
}

// Round 2
// 177.415 us; speedup vs baseline: 1.0965x; 1.0965x over previous
//
#include <hip/hip_runtime.h>
#include <hip/hip_bf16.h>
#include <stdint.h>

#define PDIM 4096
#define KSEL 3687.0f
#define NITER 50

typedef unsigned short ushort_t;
typedef __attribute__((ext_vector_type(8))) __bf16 bf16x8;
typedef __attribute__((ext_vector_type(4))) float f32x4;

typedef __attribute__((address_space(3))) void lds_void;
typedef __attribute__((address_space(1))) const void glob_void;

__device__ __forceinline__ ushort_t f32_to_bf16_rne(float f) {
  union { float f; uint32_t u; } v; v.f = f;
  uint32_t r = 0x7FFFu + ((v.u >> 16) & 1u);
  return (ushort_t)((v.u + r) >> 16);
}

__device__ __forceinline__ void async_cp16(const void* g, void* l) {
  __builtin_amdgcn_global_load_lds((glob_void*)g, (lds_void*)l, 16, 0, 0);
}

// ---------------- Kernel 1: Dykstra soft-top-k mask ----------------
__global__ __launch_bounds__(256) void dykstra_kernel(
    const float* __restrict__ alpha, float* __restrict__ a_out) {
  __shared__ float red[8];
  const int tid = threadIdx.x;
  const int lane = tid & 63;
  const int wv = tid >> 6;
  float x[16], p[16], q[16];
#pragma unroll
  for (int i = 0; i < 16; ++i) {
    x[i] = alpha[i * 256 + tid] * 100.0f;  // s = alpha / 0.01
    p[i] = 0.0f;
    q[i] = 0.0f;
  }
  for (int it = 0; it < NITER; ++it) {
    float t[16];
    float loc = 0.0f;
#pragma unroll
    for (int i = 0; i < 16; ++i) { t[i] = x[i] + p[i]; loc += t[i]; }
#pragma unroll
    for (int off = 32; off > 0; off >>= 1) loc += __shfl_down(loc, off, 64);
    const int slot = (it & 1) * 4;
    if (lane == 0) red[slot + wv] = loc;
    __syncthreads();
    const float tot = red[slot] + red[slot + 1] + red[slot + 2] + red[slot + 3];
    const float corr = (KSEL - tot) * (1.0f / 4096.0f);
#pragma unroll
    for (int i = 0; i < 16; ++i) {
      const float y = t[i] + corr;
      p[i] = t[i] - y;
      const float u = y + q[i];
      const float xn = fminf(fmaxf(u, 0.0f), 1.0f);
      q[i] = u - xn;
      x[i] = xn;
    }
  }
#pragma unroll
  for (int i = 0; i < 16; ++i) a_out[i * 256 + tid] = x[i];
}

// ---------------- Kernel 2: x fp32 -> bf16 ----------------
__global__ __launch_bounds__(256) void xconv_kernel(
    const float* __restrict__ x, ushort_t* __restrict__ Xb, int n4) {
  const int i = blockIdx.x * 256 + threadIdx.x;
  if (i >= n4) return;
  const float4 v = ((const float4*)x)[i];
  ushort4 o;
  o.x = f32_to_bf16_rne(v.x);
  o.y = f32_to_bf16_rne(v.y);
  o.z = f32_to_bf16_rne(v.z);
  o.w = f32_to_bf16_rne(v.w);
  ((ushort4*)Xb)[i] = o;
}

// ---------------- Kernel 2b: zero the output (for split-K atomics) -------
__global__ __launch_bounds__(256) void zero_kernel(float4* __restrict__ p, int n4) {
  const int i = blockIdx.x * 256 + threadIdx.x;
  if (i < n4) p[i] = (float4){0.f, 0.f, 0.f, 0.f};
}

// ---------------- Kernel 3: materialize W (row-major bf16) ----------------
// W[r][c] = a[(r-c) mod 4096] * V[(r-c) mod 4096][c]
// 64x64 W tile; 128-row fp32 V band in LDS, pad 67 (diag reads 2-way = free).
// Epilogue packs 8 bf16 -> one 16B store per lane.
__global__ __launch_bounds__(256) void wmat_kernel(
    const float* __restrict__ V, const float* __restrict__ a,
    ushort_t* __restrict__ Wb) {
  __shared__ float vt[128][67];
  const int t = threadIdx.x;
  const int r0 = blockIdx.x * 64;
  const int c0 = blockIdx.y * 64;
  const int dbase = (r0 - c0 - 63 + 2 * PDIM) & (PDIM - 1);
  // phase 1: load 128 x 64 fp32 band, scale by a[d]
  const int csub = (t & 15) * 4;
#pragma unroll
  for (int i = 0; i < 8; ++i) {
    const int ld = i * 16 + (t >> 4);
    const int d = (dbase + ld) & (PDIM - 1);
    const float av = a[d];
    const float4 vv = *(const float4*)(V + (size_t)d * PDIM + c0 + csub);
    vt[ld][csub + 0] = av * vv.x;
    vt[ld][csub + 1] = av * vv.y;
    vt[ld][csub + 2] = av * vv.z;
    vt[ld][csub + 3] = av * vv.w;
  }
  __syncthreads();
  // phase 2: diagonal gather -> pack bf16x8 -> 16B store
  const int lane = t & 63;
  const int wv = t >> 6;
  const int ry = wv * 16 + (lane & 15);
  const int s = lane >> 4;
#pragma unroll
  for (int ii = 0; ii < 2; ++ii) {
    const int cb = s * 8 + ii * 32;
    ushort_t pk[8];
#pragma unroll
    for (int j = 0; j < 8; ++j) {
      const int c = cb + j;
      pk[j] = f32_to_bf16_rne(vt[ry - c + 63][c]);
    }
    *(uint4*)(Wb + (size_t)(r0 + ry) * PDIM + c0 + cb) = *(const uint4*)pk;
  }
}

// ---------------- Kernel 4: bf16 MFMA GEMM, split-K x2 ----------------
// C[M][4096] += Xb[M][k-half] * Wb^T[k-half] ; BM=64 BN=64 BK=64.
// Grid 64 x 8 x 2 = 1024 blocks -> 4 blocks/CU for latency overlap.
// LDS chunk layout XOR-swizzled (chunk j of row at slot j^(row&7)).
__global__ __launch_bounds__(256) void gemm_kernel(
    const ushort_t* __restrict__ Xb, const ushort_t* __restrict__ Wb,
    float* __restrict__ out, int M) {
  constexpr int Kdim = 4096, Ndim = 4096, KHALF = 2048;
  __shared__ __align__(16) ushort_t As[64 * 64];
  __shared__ __align__(16) ushort_t Bs[64 * 64];
  const int tid = threadIdx.x;
  const int lane = tid & 63;
  const int w = tid >> 6;
  const int l15 = lane & 15;
  const int quad = lane >> 4;
  const int m0 = blockIdx.y * 64;
  const int n0 = blockIdx.x * 64;
  const int kbase = blockIdx.z * KHALF;
  const int arow = lane >> 3;  // 0..7
  const int aslot = lane & 7;

  f32x4 acc[4];
#pragma unroll
  for (int mt = 0; mt < 4; ++mt) acc[mt] = (f32x4){0.f, 0.f, 0.f, 0.f};

  for (int it = 0; it < KHALF / 64; ++it) {
    const int k0 = kbase + it * 64;
#pragma unroll
    for (int s = w; s < 8; s += 4) {
      const int row = s * 8 + arow;
      const int j = aslot ^ (row & 7);
      async_cp16(Xb + (size_t)(m0 + row) * Kdim + k0 + j * 8,
                 (char*)As + (size_t)s * 1024);
      async_cp16(Wb + (size_t)(n0 + row) * Kdim + k0 + j * 8,
                 (char*)Bs + (size_t)s * 1024);
    }
    __syncthreads();
#pragma unroll
    for (int kk = 0; kk < 64; kk += 32) {
      const int cj = (kk >> 3) + quad;
      bf16x8 bfv;
      {
        const int row = w * 16 + l15;
        bfv = *(const bf16x8*)&Bs[(row * 8 + (cj ^ (row & 7))) * 8];
      }
#pragma unroll
      for (int mt = 0; mt < 4; ++mt) {
        const int row = mt * 16 + l15;
        const bf16x8 af = *(const bf16x8*)&As[(row * 8 + (cj ^ (row & 7))) * 8];
        acc[mt] = __builtin_amdgcn_mfma_f32_16x16x32_bf16(af, bfv, acc[mt], 0, 0, 0);
      }
    }
    __syncthreads();
  }
  // epilogue: C/D layout col=lane&15 (n), row=quad*4+reg (m); split-K atomic
#pragma unroll
  for (int mt = 0; mt < 4; ++mt) {
    const int mb = m0 + mt * 16 + quad * 4;
    const int n = n0 + w * 16 + l15;
#pragma unroll
    for (int r = 0; r < 4; ++r)
      atomicAdd(&out[(size_t)(mb + r) * Ndim + n], acc[mt][r]);
  }
}

extern "C" void kernel_launch(void* const* d_in, const int* in_sizes, int n_in,
                              void* d_out, int out_size, void* d_ws,
                              size_t ws_size, hipStream_t stream) {
  const float* x = (const float*)d_in[0];
  const float* V = (const float*)d_in[1];
  const float* alpha = (const float*)d_in[2];
  float* out = (float*)d_out;
  const int M = in_sizes[0] / PDIM;  // 512

  // workspace layout: a (16KB) | Xb bf16 (M*4096*2) | Wb bf16 (4096*4096*2)
  float* a_mask = (float*)d_ws;
  ushort_t* Xb = (ushort_t*)((char*)d_ws + 16 * 1024);
  ushort_t* Wb = Xb + (size_t)M * PDIM;

  dykstra_kernel<<<1, 256, 0, stream>>>(alpha, a_mask);
  const int n4 = (M * PDIM) / 4;
  xconv_kernel<<<(n4 + 255) / 256, 256, 0, stream>>>(x, Xb, n4);
  zero_kernel<<<(out_size / 4 + 255) / 256, 256, 0, stream>>>((float4*)out,
                                                              out_size / 4);
  wmat_kernel<<<dim3(PDIM / 64, PDIM / 64), 256, 0, stream>>>(V, a_mask, Wb);
  gemm_kernel<<<dim3(PDIM / 64, M / 64, 2), 256, 0, stream>>>(Xb, Wb, out, M);
}

// Round 3
// 164.785 us; speedup vs baseline: 1.1805x; 1.0766x over previous
//
#include <hip/hip_runtime.h>
#include <hip/hip_bf16.h>
#include <stdint.h>

#define PDIM 4096
#define KSEL 3687.0f
#define NITER 50

typedef unsigned short ushort_t;
typedef __attribute__((ext_vector_type(8))) __bf16 bf16x8;
typedef __attribute__((ext_vector_type(4))) float f32x4;

typedef __attribute__((address_space(3))) void lds_void;
typedef __attribute__((address_space(1))) const void glob_void;

__device__ __forceinline__ ushort_t f32_to_bf16_rne(float f) {
  union { float f; uint32_t u; } v; v.f = f;
  uint32_t r = 0x7FFFu + ((v.u >> 16) & 1u);
  return (ushort_t)((v.u + r) >> 16);
}

__device__ __forceinline__ void async_cp16(const void* g, void* l) {
  __builtin_amdgcn_global_load_lds((glob_void*)g, (lds_void*)l, 16, 0, 0);
}

// ---------------- Kernel 1: fused Dykstra (block 0) + x->bf16 (rest) ------
// Dykstra: p = t - y = -corr is lane-uniform -> keep p as a scalar.
__global__ __launch_bounds__(256) void prep_kernel(
    const float* __restrict__ alpha, float* __restrict__ a_out,
    const float* __restrict__ x, ushort_t* __restrict__ Xb, int n4) {
  if (blockIdx.x != 0) {
    const int i = (blockIdx.x - 1) * 256 + threadIdx.x;
    if (i < n4) {
      const float4 v = ((const float4*)x)[i];
      ushort4 o;
      o.x = f32_to_bf16_rne(v.x);
      o.y = f32_to_bf16_rne(v.y);
      o.z = f32_to_bf16_rne(v.z);
      o.w = f32_to_bf16_rne(v.w);
      ((ushort4*)Xb)[i] = o;
    }
    return;
  }
  __shared__ float red[8];
  const int tid = threadIdx.x;
  const int lane = tid & 63;
  const int wv = tid >> 6;
  float xx[16], q[16];
  float p = 0.0f;
#pragma unroll
  for (int i = 0; i < 16; ++i) {
    xx[i] = alpha[i * 256 + tid] * 100.0f;  // s = alpha / 0.01
    q[i] = 0.0f;
  }
  for (int it = 0; it < NITER; ++it) {
    float t[16];
    float loc = 0.0f;
#pragma unroll
    for (int i = 0; i < 16; ++i) { t[i] = xx[i] + p; loc += t[i]; }
#pragma unroll
    for (int off = 32; off > 0; off >>= 1) loc += __shfl_down(loc, off, 64);
    const int slot = (it & 1) * 4;
    if (lane == 0) red[slot + wv] = loc;
    __syncthreads();
    const float tot = red[slot] + red[slot + 1] + red[slot + 2] + red[slot + 3];
    const float corr = (KSEL - tot) * (1.0f / 4096.0f);
    p = -corr;
#pragma unroll
    for (int i = 0; i < 16; ++i) {
      const float y = t[i] + corr;
      const float u = y + q[i];
      const float xn = fminf(fmaxf(u, 0.0f), 1.0f);
      q[i] = u - xn;
      xx[i] = xn;
    }
  }
#pragma unroll
  for (int i = 0; i < 16; ++i) a_out[i * 256 + tid] = xx[i];
}

// ---------------- Kernel 2: materialize W (row-major bf16) ----------------
// W[r][c] = a[(r-c) mod 4096] * V[(r-c) mod 4096][c]
// 128x64 W tile; 192-row fp32 V band in LDS (1.5x read amplification).
__global__ __launch_bounds__(256) void wmat_kernel(
    const float* __restrict__ V, const float* __restrict__ a,
    ushort_t* __restrict__ Wb) {
  __shared__ float vt[192][67];
  const int t = threadIdx.x;
  const int r0 = blockIdx.x * 128;
  const int c0 = blockIdx.y * 64;
  const int dbase = (r0 - c0 - 63 + 2 * PDIM) & (PDIM - 1);
  // phase 1: load 192 x 64 fp32 band, scale by a[d]
  const int csub = (t & 15) * 4;
  const int rsub = t >> 4;
#pragma unroll
  for (int i = 0; i < 12; ++i) {
    const int ld = i * 16 + rsub;
    const int d = (dbase + ld) & (PDIM - 1);
    const float av = a[d];
    const float4 vv = *(const float4*)(V + (size_t)d * PDIM + c0 + csub);
    vt[ld][csub + 0] = av * vv.x;
    vt[ld][csub + 1] = av * vv.y;
    vt[ld][csub + 2] = av * vv.z;
    vt[ld][csub + 3] = av * vv.w;
  }
  __syncthreads();
  // phase 2: diagonal gather -> pack bf16x8 -> 16B store (4 chunks/thread)
#pragma unroll
  for (int k = 0; k < 4; ++k) {
    const int ry = (t >> 3) + k * 32;
    const int cb = (t & 7) * 8;
    ushort_t pk[8];
#pragma unroll
    for (int j = 0; j < 8; ++j) {
      const int c = cb + j;
      pk[j] = f32_to_bf16_rne(vt[ry - c + 63][c]);
    }
    *(uint4*)(Wb + (size_t)(r0 + ry) * PDIM + c0 + cb) = *(const uint4*)pk;
  }
}

// ---------------- Kernel 3: bf16 MFMA GEMM, split-K x4, private partials --
// C_z[M][4096] = Xb[M][kq] * Wb^T[kq] ; BM=64 BN=128 BK=64, KQ=1024.
// Grid 32 x 8 x 4 = 1024 blocks -> 4 blocks/CU. No atomics.
__global__ __launch_bounds__(256) void gemm_kernel(
    const ushort_t* __restrict__ Xb, const ushort_t* __restrict__ Wb,
    float* __restrict__ par, int M) {
  constexpr int Kdim = 4096, Ndim = 4096, KQ = 1024;
  __shared__ __align__(16) ushort_t As[64 * 64];
  __shared__ __align__(16) ushort_t Bs[128 * 64];
  const int tid = threadIdx.x;
  const int lane = tid & 63;
  const int w = tid >> 6;
  const int l15 = lane & 15;
  const int quad = lane >> 4;
  const int m0 = blockIdx.y * 64;
  const int n0 = blockIdx.x * 128;
  const int kbase = blockIdx.z * KQ;
  float* outp = par + (size_t)blockIdx.z * ((size_t)512 * Ndim);
  const int arow = lane >> 3;  // 0..7
  const int aslot = lane & 7;

  f32x4 acc[4][2];
#pragma unroll
  for (int mt = 0; mt < 4; ++mt)
#pragma unroll
    for (int nt = 0; nt < 2; ++nt) acc[mt][nt] = (f32x4){0.f, 0.f, 0.f, 0.f};

  for (int it = 0; it < KQ / 64; ++it) {
    const int k0 = kbase + it * 64;
#pragma unroll
    for (int s = w; s < 8; s += 4) {
      const int row = s * 8 + arow;
      const int j = aslot ^ (row & 7);
      async_cp16(Xb + (size_t)(m0 + row) * Kdim + k0 + j * 8,
                 (char*)As + (size_t)s * 1024);
    }
#pragma unroll
    for (int s = w; s < 16; s += 4) {
      const int row = s * 8 + arow;
      const int j = aslot ^ (row & 7);
      async_cp16(Wb + (size_t)(n0 + row) * Kdim + k0 + j * 8,
                 (char*)Bs + (size_t)s * 1024);
    }
    __syncthreads();
#pragma unroll
    for (int kk = 0; kk < 64; kk += 32) {
      const int cj = (kk >> 3) + quad;
      bf16x8 af[4], bfv[2];
#pragma unroll
      for (int mt = 0; mt < 4; ++mt) {
        const int row = mt * 16 + l15;
        af[mt] = *(const bf16x8*)&As[(row * 8 + (cj ^ (row & 7))) * 8];
      }
#pragma unroll
      for (int nt = 0; nt < 2; ++nt) {
        const int row = w * 32 + nt * 16 + l15;
        bfv[nt] = *(const bf16x8*)&Bs[(row * 8 + (cj ^ (row & 7))) * 8];
      }
#pragma unroll
      for (int mt = 0; mt < 4; ++mt)
#pragma unroll
        for (int nt = 0; nt < 2; ++nt)
          acc[mt][nt] = __builtin_amdgcn_mfma_f32_16x16x32_bf16(
              af[mt], bfv[nt], acc[mt][nt], 0, 0, 0);
    }
    __syncthreads();
  }
  // epilogue: C/D layout col=lane&15 (n), row=quad*4+reg (m)
#pragma unroll
  for (int mt = 0; mt < 4; ++mt) {
#pragma unroll
    for (int nt = 0; nt < 2; ++nt) {
      const int mb = m0 + mt * 16 + quad * 4;
      const int n = n0 + w * 32 + nt * 16 + l15;
#pragma unroll
      for (int r = 0; r < 4; ++r)
        outp[(size_t)(mb + r) * Ndim + n] = acc[mt][nt][r];
    }
  }
}

// ---------------- Kernel 4: sum 4 split-K partials ----------------
__global__ __launch_bounds__(256) void combine_kernel(
    const float4* __restrict__ par, float4* __restrict__ out, int n4) {
  const int i = blockIdx.x * 256 + threadIdx.x;
  if (i >= n4) return;
  const float4 a = par[i];
  const float4 b = par[i + n4];
  const float4 c = par[i + 2 * n4];
  const float4 d = par[i + 3 * n4];
  float4 o;
  o.x = (a.x + b.x) + (c.x + d.x);
  o.y = (a.y + b.y) + (c.y + d.y);
  o.z = (a.z + b.z) + (c.z + d.z);
  o.w = (a.w + b.w) + (c.w + d.w);
  out[i] = o;
}

extern "C" void kernel_launch(void* const* d_in, const int* in_sizes, int n_in,
                              void* d_out, int out_size, void* d_ws,
                              size_t ws_size, hipStream_t stream) {
  const float* x = (const float*)d_in[0];
  const float* V = (const float*)d_in[1];
  const float* alpha = (const float*)d_in[2];
  float* out = (float*)d_out;
  const int M = in_sizes[0] / PDIM;  // 512

  // ws: a(16KB) | Xb bf16 (4MB) | Wb bf16 (32MB) | partials fp32 4x8MB
  float* a_mask = (float*)d_ws;
  ushort_t* Xb = (ushort_t*)((char*)d_ws + 16 * 1024);
  ushort_t* Wb = Xb + (size_t)M * PDIM;
  float* par = (float*)(Wb + (size_t)PDIM * PDIM);

  const int n4x = (M * PDIM) / 4;  // 524288
  prep_kernel<<<1 + (n4x + 255) / 256, 256, 0, stream>>>(alpha, a_mask, x, Xb,
                                                         n4x);
  wmat_kernel<<<dim3(PDIM / 128, PDIM / 64), 256, 0, stream>>>(V, a_mask, Wb);
  gemm_kernel<<<dim3(PDIM / 128, M / 64, 4), 256, 0, stream>>>(Xb, Wb, par, M);
  const int n4o = out_size / 4;
  combine_kernel<<<(n4o + 255) / 256, 256, 0, stream>>>((const float4*)par,
                                                        (float4*)out, n4o);
}